// Round 2
// baseline (110.738 us; speedup 1.0000x reference)
//
#include <hip/hip_runtime.h>

typedef __bf16 v8bf __attribute__((ext_vector_type(8)));
typedef float v4f __attribute__((ext_vector_type(4)));
typedef unsigned short u16x8 __attribute__((ext_vector_type(8)));

__device__ __forceinline__ unsigned short f2bf(float f) {
    unsigned int u = __float_as_uint(f);
    u += 0x7FFFu + ((u >> 16) & 1u);   // round-to-nearest-even
    return (unsigned short)(u >> 16);
}

__device__ __forceinline__ v8bf ld_bf8(const unsigned short* p) {
    u16x8 r = *(const u16x8*)p;
    return __builtin_bit_cast(v8bf, r);
}

// ---------------- Kernel A: build V = U[:, :64] (one column per block) ----------------
__global__ __launch_bounds__(256) void build_V(
        const float* __restrict__ rx0, const float* __restrict__ ry0,
        const float* __restrict__ ry1,
        unsigned short* __restrict__ Vre, unsigned short* __restrict__ Vim)
{
    __shared__ float sre[1024];
    __shared__ float sim[1024];
    const int c = blockIdx.x;     // feature column 0..63
    const int t = threadIdx.x;

    for (int k = 0; k < 4; ++k) {
        int i = t + k * 256;
        sre[i] = (i == c) ? 1.0f : 0.0f;
        sim[i] = 0.0f;
    }
    __syncthreads();

    // Stage 1: G_j = RY(ry0_j) * RX(rx0_j) on qubit j (qubit j <-> bit 9-j)
    for (int j = 0; j < 10; ++j) {
        float hx = 0.5f * rx0[j], hy = 0.5f * ry0[j];
        float cx = cosf(hx), sx = sinf(hx);
        float cy = cosf(hy), sy = sinf(hy);
        float g00r =  cy * cx, g00i =  sy * sx;
        float g01r = -sy * cx, g01i = -cy * sx;
        float g10r =  sy * cx, g10i = -cy * sx;
        float g11r =  cy * cx, g11i = -sy * sx;
        int p = 9 - j;
        int lowmask = (1 << p) - 1;
        #pragma unroll
        for (int it = 0; it < 2; ++it) {
            int idx = t + it * 256;
            int a = ((idx >> p) << (p + 1)) | (idx & lowmask);
            int b = a | (1 << p);
            float ar = sre[a], ai = sim[a], br = sre[b], bi = sim[b];
            sre[a] = g00r*ar - g00i*ai + g01r*br - g01i*bi;
            sim[a] = g00r*ai + g00i*ar + g01r*bi + g01i*br;
            sre[b] = g10r*ar - g10i*ai + g11r*br - g11i*bi;
            sim[b] = g10r*ai + g10i*ar + g11r*bi + g11i*br;
        }
        __syncthreads();
    }
    // Stage 2: CNOT ring j -> (j+1)%10
    for (int j = 0; j < 10; ++j) {
        int pc = 9 - j;
        int pt = 9 - ((j + 1) % 10);
        int p1 = pc < pt ? pc : pt;
        int p2 = pc < pt ? pt : pc;
        int x1 = ((t >> p1) << (p1 + 1)) | (t & ((1 << p1) - 1));
        int x2 = ((x1 >> p2) << (p2 + 1)) | (x1 & ((1 << p2) - 1));
        int i0 = x2 | (1 << pc);          // control=1, target=0
        int i1 = i0 | (1 << pt);
        float r0 = sre[i0], q0 = sim[i0];
        sre[i0] = sre[i1]; sim[i0] = sim[i1];
        sre[i1] = r0;      sim[i1] = q0;
        __syncthreads();
    }
    // Stage 3: RY(ry1_j)
    for (int j = 0; j < 10; ++j) {
        float hy = 0.5f * ry1[j];
        float cy = cosf(hy), sy = sinf(hy);
        int p = 9 - j;
        int lowmask = (1 << p) - 1;
        #pragma unroll
        for (int it = 0; it < 2; ++it) {
            int idx = t + it * 256;
            int a = ((idx >> p) << (p + 1)) | (idx & lowmask);
            int b = a | (1 << p);
            float ar = sre[a], ai = sim[a], br = sre[b], bi = sim[b];
            sre[a] = cy*ar - sy*br;  sim[a] = cy*ai - sy*bi;
            sre[b] = sy*ar + cy*br;  sim[b] = sy*ai + cy*bi;
        }
        __syncthreads();
    }
    for (int k = 0; k < 4; ++k) {
        int i = t + k * 256;
        Vre[i * 64 + c] = f2bf(sre[i]);
        Vim[i * 64 + c] = f2bf(sim[i]);
    }
}

// ---------------- Kernel B: fused  out = (|xn @ V^T|^2) @ SIGN^T ----------------
#define LDP 72   // padded LDS row stride (bf16 elems): 144 B, 16B-aligned rows

__global__ __launch_bounds__(256) void qsa_fused(
        const float* __restrict__ x,
        const unsigned short* __restrict__ Vre,
        const unsigned short* __restrict__ Vim,
        float* __restrict__ out)
{
    __shared__ alignas(16) unsigned short xn[64][LDP];
    __shared__ alignas(16) unsigned short vre[64][LDP];
    __shared__ alignas(16) unsigned short vim[64][LDP];
    __shared__ alignas(16) unsigned short pr[64][LDP];

    const int tid = threadIdx.x;
    const int w = tid >> 6;           // wave 0..3  (owns tokens w*16 .. w*16+15)
    const int l = tid & 63;
    const int m0 = blockIdx.x * 64;

    // ---- load + normalize x tile (64 tokens x 64 feats) ----
    {
        int tok = tid >> 2, part = tid & 3;
        const float4* src = (const float4*)(x + (size_t)(m0 + tok) * 64 + part * 16);
        float4 v[4];
        float ss = 0.f;
        #pragma unroll
        for (int q = 0; q < 4; ++q) {
            v[q] = src[q];
            ss += v[q].x*v[q].x + v[q].y*v[q].y + v[q].z*v[q].z + v[q].w*v[q].w;
        }
        ss += __shfl_xor(ss, 1);
        ss += __shfl_xor(ss, 2);
        float rn = rsqrtf(ss);
        unsigned short* dst = &xn[tok][part * 16];
        #pragma unroll
        for (int q = 0; q < 4; ++q) {
            dst[q*4+0] = f2bf(v[q].x * rn);
            dst[q*4+1] = f2bf(v[q].y * rn);
            dst[q*4+2] = f2bf(v[q].z * rn);
            dst[q*4+3] = f2bf(v[q].w * rn);
        }
    }
    __syncthreads();

    const int l15 = l & 15, lh = l >> 4;

    // A-fragments (tokens of this wave), K=64 feats in 2 k-steps
    v8bf a0 = ld_bf8(&xn[w*16 + l15][lh*8]);
    v8bf a1 = ld_bf8(&xn[w*16 + l15][32 + lh*8]);

    v4f oacc[4];
    #pragma unroll
    for (int nb = 0; nb < 4; ++nb) oacc[nb] = (v4f){0.f,0.f,0.f,0.f};

    for (int s0 = 0; s0 < 1024; s0 += 64) {
        // stage V chunk (64 states x 64 feats, re+im) into LDS
        #pragma unroll
        for (int it = 0; it < 2; ++it) {
            int idx = tid + it * 256;
            int row = idx >> 3, c8 = (idx & 7) * 8;
            *(u16x8*)&vre[row][c8] = *(const u16x8*)(Vre + (size_t)(s0 + row) * 64 + c8);
            *(u16x8*)&vim[row][c8] = *(const u16x8*)(Vim + (size_t)(s0 + row) * 64 + c8);
        }
        __syncthreads();

        // matmul1: psi(tokens x 64 states) = xn @ V^T, complex as 2 real GEMMs
        v4f pre[4], pim[4];
        #pragma unroll
        for (int nb = 0; nb < 4; ++nb) {
            v8bf br0 = ld_bf8(&vre[nb*16 + l15][lh*8]);
            v8bf br1 = ld_bf8(&vre[nb*16 + l15][32 + lh*8]);
            v8bf bi0 = ld_bf8(&vim[nb*16 + l15][lh*8]);
            v8bf bi1 = ld_bf8(&vim[nb*16 + l15][32 + lh*8]);
            v4f z = (v4f){0.f,0.f,0.f,0.f};
            v4f r = __builtin_amdgcn_mfma_f32_16x16x32_bf16(a0, br0, z, 0, 0, 0);
            r     = __builtin_amdgcn_mfma_f32_16x16x32_bf16(a1, br1, r, 0, 0, 0);
            v4f q = __builtin_amdgcn_mfma_f32_16x16x32_bf16(a0, bi0, z, 0, 0, 0);
            q     = __builtin_amdgcn_mfma_f32_16x16x32_bf16(a1, bi1, q, 0, 0, 0);
            pre[nb] = r; pim[nb] = q;
        }

        // probs = re^2 + im^2 (fp32) -> bf16 in LDS (C/D layout: row=token, col=state)
        #pragma unroll
        for (int nb = 0; nb < 4; ++nb) {
            #pragma unroll
            for (int r = 0; r < 4; ++r) {
                float p = pre[nb][r]*pre[nb][r] + pim[nb][r]*pim[nb][r];
                pr[w*16 + lh*4 + r][nb*16 + l15] = f2bf(p);
            }
        }

        // matmul2: out(tokens x 64 h) += probs @ SIGN^T  (K = 64 states of this chunk)
        v8bf pa0 = ld_bf8(&pr[w*16 + l15][lh*8]);
        v8bf pa1 = ld_bf8(&pr[w*16 + l15][32 + lh*8]);
        #pragma unroll
        for (int nb = 0; nb < 4; ++nb) {
            unsigned mask = (unsigned)(nb*16 + l15 + 1);   // Z-string mask = h+1
            u16x8 sA, sB;
            #pragma unroll
            for (int j = 0; j < 8; ++j) {
                int sa = s0 + lh*8 + j;
                int sb = sa + 32;
                sA[j] = (__popc(sa & mask) & 1) ? 0xBF80 : 0x3F80;  // -1 : +1 (bf16)
                sB[j] = (__popc(sb & mask) & 1) ? 0xBF80 : 0x3F80;
            }
            oacc[nb] = __builtin_amdgcn_mfma_f32_16x16x32_bf16(pa0, __builtin_bit_cast(v8bf, sA), oacc[nb], 0, 0, 0);
            oacc[nb] = __builtin_amdgcn_mfma_f32_16x16x32_bf16(pa1, __builtin_bit_cast(v8bf, sB), oacc[nb], 0, 0, 0);
        }
        __syncthreads();   // protect vre/vim before next chunk's staging
    }

    // write out: out[token][h], fp32
    #pragma unroll
    for (int nb = 0; nb < 4; ++nb) {
        #pragma unroll
        for (int r = 0; r < 4; ++r) {
            out[(size_t)(m0 + w*16 + lh*4 + r) * 64 + nb*16 + l15] = oacc[nb][r];
        }
    }
}

extern "C" void kernel_launch(void* const* d_in, const int* in_sizes, int n_in,
                              void* d_out, int out_size, void* d_ws, size_t ws_size,
                              hipStream_t stream) {
    const float* x   = (const float*)d_in[0];
    const float* rx0 = (const float*)d_in[1];
    const float* ry0 = (const float*)d_in[2];
    const float* ry1 = (const float*)d_in[3];
    float* out = (float*)d_out;

    unsigned short* Vre = (unsigned short*)d_ws;            // 1024*64 bf16
    unsigned short* Vim = Vre + 1024 * 64;                  // 1024*64 bf16

    const int M = in_sizes[0] / 64;                         // tokens (B*T)

    build_V<<<64, 256, 0, stream>>>(rx0, ry0, ry1, Vre, Vim);
    qsa_fused<<<M / 64, 256, 0, stream>>>(x, Vre, Vim, out);
}